// Round 2
// baseline (257.718 us; speedup 1.0000x reference)
//
#include <hip/hip_runtime.h>
#include <hip/hip_bf16.h>

typedef __bf16 bf16x8 __attribute__((ext_vector_type(8)));
typedef float  f32x16 __attribute__((ext_vector_type(16)));
typedef float  f32x4  __attribute__((ext_vector_type(4)));

#define NLAYERS 19
#define BROWS   (1u << 20)
#define NTILES  (BROWS / 32)      // 32768 tiles of 32 rows
#define NBLOCKS 256
#define TPB     1024
#define NWAVES  (NBLOCKS * (TPB / 64))   // 4096 waves

// ---- helpers ------------------------------------------------------------

// pack bf16(trunc(a)) into low16, bf16(trunc(b)) into high16 (one v_perm_b32)
__device__ __forceinline__ unsigned pack_hi(float a, float b) {
    return __builtin_amdgcn_perm(__float_as_uint(b), __float_as_uint(a), 0x07060302u);
}

// f32 value of the bf16-truncation of v (exact)
__device__ __forceinline__ float trunc_bf16_f32(float v) {
    return __uint_as_float(__float_as_uint(v) & 0xFFFF0000u);
}

__device__ __forceinline__ unsigned cvt_pk_bf16(float a, float b) {
    unsigned r;
    asm("v_cvt_pk_bf16_f32 %0, %1, %2" : "=v"(r) : "v"(a), "v"(b));
    return r;
}

__device__ __forceinline__ float fast_rcp(float a) {
    float r;
    asm("v_rcp_f32 %0, %1" : "=v"(r) : "v"(a));
    return r;
}

// v_permlane32_swap_b32: a' = [a.lo_lanes | b.lo_lanes], b' = [a.hi_lanes | b.hi_lanes]
__device__ __forceinline__ void pl32_swap(unsigned& a, unsigned& b) {
    asm volatile("v_permlane32_swap_b32 %0, %1" : "+v"(a), "+v"(b));
}

__device__ __forceinline__ unsigned short bf16_rne_bits(float f) {
    __hip_bfloat16 b = __float2bfloat16(f);
    return *reinterpret_cast<unsigned short*>(&b);
}

__device__ __forceinline__ f32x16 mfma(bf16x8 a, bf16x8 b, f32x16 c) {
    return __builtin_amdgcn_mfma_f32_32x32x16_bf16(a, b, c, 0, 0, 0);
}

union FragU { unsigned u[4]; bf16x8 v; };

// softsign 16 accumulator values -> sv[]
__device__ __forceinline__ void softsign16(const f32x16& c, float* sv) {
#pragma unroll
    for (int r = 0; r < 16; ++r) {
        float v = c[r];
        sv[r] = v * fast_rcp(1.0f + __builtin_fabsf(v));
    }
}

// Repack softsign outputs (C/D layout) into next-layer B fragments (hi/lo bf16).
// C/D: lane half h=lane>>5 holds feats (r&3)+8*(r>>2)+4h for r=0..15.
// B frag K-step s: lane half h needs feats 16s+8h+e, e=0..7.
__device__ __forceinline__ void repack(const float* sv, bf16x8* bhi, bf16x8* blo) {
#pragma unroll
    for (int s = 0; s < 2; ++s) {
        const float* p = sv + 8 * s;
        // hi parts (bf16 truncation of value)
        unsigned p00 = pack_hi(p[0], p[1]);
        unsigned p01 = pack_hi(p[2], p[3]);
        unsigned p10 = pack_hi(p[4], p[5]);
        unsigned p11 = pack_hi(p[6], p[7]);
        pl32_swap(p00, p10);   // p00 -> e0,e1   p10 -> e4,e5
        pl32_swap(p01, p11);   // p01 -> e2,e3   p11 -> e6,e7
        FragU H; H.u[0] = p00; H.u[1] = p01; H.u[2] = p10; H.u[3] = p11;
        bhi[s] = H.v;
        // lo parts (RNE of residual)
        float l0 = p[0] - trunc_bf16_f32(p[0]);
        float l1 = p[1] - trunc_bf16_f32(p[1]);
        float l2 = p[2] - trunc_bf16_f32(p[2]);
        float l3 = p[3] - trunc_bf16_f32(p[3]);
        float l4 = p[4] - trunc_bf16_f32(p[4]);
        float l5 = p[5] - trunc_bf16_f32(p[5]);
        float l6 = p[6] - trunc_bf16_f32(p[6]);
        float l7 = p[7] - trunc_bf16_f32(p[7]);
        unsigned q00 = cvt_pk_bf16(l0, l1);
        unsigned q01 = cvt_pk_bf16(l2, l3);
        unsigned q10 = cvt_pk_bf16(l4, l5);
        unsigned q11 = cvt_pk_bf16(l6, l7);
        pl32_swap(q00, q10);
        pl32_swap(q01, q11);
        FragU L; L.u[0] = q00; L.u[1] = q01; L.u[2] = q10; L.u[3] = q11;
        blo[s] = L.v;
    }
}

// ---- kernel -------------------------------------------------------------

extern "C" __global__ void __launch_bounds__(TPB)
actuatornet_kernel(const float* __restrict__ x,  const float* __restrict__ W1,
                   const float* __restrict__ b1, const float* __restrict__ Wh,
                   const float* __restrict__ bh, const float* __restrict__ Wout,
                   const float* __restrict__ bout, float* __restrict__ out)
{
    // LDS: W^T A-fragments, hi/lo bf16, laid out so lane reads 16B contiguous.
    __shared__ unsigned short s_wa_hi[NLAYERS * 2 * 64 * 8];   // 38912 B
    __shared__ unsigned short s_wa_lo[NLAYERS * 2 * 64 * 8];   // 38912 B
    __shared__ unsigned short s_w1_hi[64 * 8];                 // 1024 B
    __shared__ unsigned short s_w1_lo[64 * 8];                 // 1024 B
    __shared__ float          s_bh[NLAYERS * 32];              // 2432 B
    __shared__ float          s_b1[32];
    __shared__ float          s_wout[32];

    const int tid = threadIdx.x;

    // ---- weight prep: split fp32 -> bf16 hi/lo in MFMA A-fragment order ----
    // A = W^T for layer `lay`, K-step s: lane l element e holds
    //   A[row = fo = l&31][k = fi-16s = 8*(l>>5)+e]  ==  W[fi][fo]
    for (int idx = tid; idx < NLAYERS * 2 * 64 * 8; idx += TPB) {
        int e = idx & 7, l = (idx >> 3) & 63, s = (idx >> 9) & 1, lay = idx >> 10;
        int fi = 16 * s + 8 * (l >> 5) + e;
        int fo = l & 31;
        float w = Wh[lay * 1024 + fi * 32 + fo];
        unsigned wb = __float_as_uint(w);
        s_wa_hi[idx] = (unsigned short)(wb >> 16);
        s_wa_lo[idx] = bf16_rne_bits(w - __uint_as_float(wb & 0xFFFF0000u));
    }
    for (int idx = tid; idx < 64 * 8; idx += TPB) {
        int e = idx & 7, l = idx >> 3;
        int k = 8 * (l >> 5) + e;             // fc1 K=16 (6 real + zero pad)
        int fo = l & 31;
        float w = (k < 6) ? W1[k * 32 + fo] : 0.0f;
        unsigned wb = __float_as_uint(w);
        s_w1_hi[idx] = (unsigned short)(wb >> 16);
        s_w1_lo[idx] = bf16_rne_bits(w - __uint_as_float(wb & 0xFFFF0000u));
    }
    if (tid < NLAYERS * 32) s_bh[tid] = bh[tid];
    if (tid < 32) { s_b1[tid] = b1[tid]; s_wout[tid] = Wout[tid]; }
    const float bout_v = bout[0];
    __syncthreads();

    const int lane = tid & 63;
    const int col  = lane & 31;       // batch column within tile
    const int h    = lane >> 5;       // lane half
    const int wid  = blockIdx.x * (TPB / 64) + (tid >> 6);   // 0..4095

    const unsigned short* wa_hi_lane = s_wa_hi + lane * 8;
    const unsigned short* wa_lo_lane = s_wa_lo + lane * 8;
    const bf16x8 a1h = *(const bf16x8*)(s_w1_hi + lane * 8);
    const bf16x8 a1l = *(const bf16x8*)(s_w1_lo + lane * 8);
    const unsigned hm = (h == 0) ? 0xFFFFFFFFu : 0u;

    for (int tile = wid; tile < NTILES; tile += NWAVES) {
        const int base = tile * 32;

        // ---- fc1: load x row (6 floats), build B fragment (only h=0, e<6 nonzero)
        const float2* xr = (const float2*)(x + (size_t)(base + col) * 6);
        float2 xa = xr[0], xb = xr[1], xc = xr[2];
        FragU BH, BL;
        BH.u[0] = pack_hi(xa.x, xa.y) & hm;
        BH.u[1] = pack_hi(xb.x, xb.y) & hm;
        BH.u[2] = pack_hi(xc.x, xc.y) & hm;
        BH.u[3] = 0u;
        BL.u[0] = cvt_pk_bf16(xa.x - trunc_bf16_f32(xa.x), xa.y - trunc_bf16_f32(xa.y)) & hm;
        BL.u[1] = cvt_pk_bf16(xb.x - trunc_bf16_f32(xb.x), xb.y - trunc_bf16_f32(xb.y)) & hm;
        BL.u[2] = cvt_pk_bf16(xc.x - trunc_bf16_f32(xc.x), xc.y - trunc_bf16_f32(xc.y)) & hm;
        BL.u[3] = 0u;

        f32x16 c;
        {
            const float* bb = s_b1 + 4 * h;
#pragma unroll
            for (int q = 0; q < 4; ++q) {
                const f32x4 t = *(const f32x4*)(bb + 8 * q);
                c[4 * q + 0] = t[0]; c[4 * q + 1] = t[1];
                c[4 * q + 2] = t[2]; c[4 * q + 3] = t[3];
            }
        }
        c = mfma(a1h, BH.v, c);
        c = mfma(a1h, BL.v, c);
        c = mfma(a1l, BH.v, c);

        float sv[16];
        softsign16(c, sv);
        bf16x8 hhi[2], hlo[2];
        repack(sv, hhi, hlo);

        // ---- 19 hidden layers
        for (int lay = 0; lay < NLAYERS; ++lay) {
            {
                const float* bb = s_bh + lay * 32 + 4 * h;
#pragma unroll
                for (int q = 0; q < 4; ++q) {
                    const f32x4 t = *(const f32x4*)(bb + 8 * q);
                    c[4 * q + 0] = t[0]; c[4 * q + 1] = t[1];
                    c[4 * q + 2] = t[2]; c[4 * q + 3] = t[3];
                }
            }
#pragma unroll
            for (int s = 0; s < 2; ++s) {
                const bf16x8 ah = *(const bf16x8*)(wa_hi_lane + (lay * 2 + s) * 512);
                const bf16x8 al = *(const bf16x8*)(wa_lo_lane + (lay * 2 + s) * 512);
                c = mfma(ah, hhi[s], c);
                c = mfma(ah, hlo[s], c);
                c = mfma(al, hhi[s], c);
            }
            softsign16(c, sv);
            if (lay != NLAYERS - 1) repack(sv, hhi, hlo);
        }

        // ---- fc6: dot(h, Wout) + bout
        float dot = 0.0f;
        {
            const float* wo = s_wout + 4 * h;
#pragma unroll
            for (int q = 0; q < 4; ++q) {
                const f32x4 w4 = *(const f32x4*)(wo + 8 * q);
                dot += sv[4 * q + 0] * w4[0] + sv[4 * q + 1] * w4[1]
                     + sv[4 * q + 2] * w4[2] + sv[4 * q + 3] * w4[3];
            }
        }
        float other = __shfl_xor(dot, 32, 64);
        dot += other;
        if (h == 0) out[base + col] = dot + bout_v;
    }
}

// ---- launch -------------------------------------------------------------

extern "C" void kernel_launch(void* const* d_in, const int* in_sizes, int n_in,
                              void* d_out, int out_size, void* d_ws, size_t ws_size,
                              hipStream_t stream) {
    const float* x    = (const float*)d_in[0];
    const float* W1   = (const float*)d_in[1];
    const float* b1   = (const float*)d_in[2];
    const float* bh   = nullptr; (void)bh;
    const float* Wh   = (const float*)d_in[3];
    const float* bh2  = (const float*)d_in[4];
    const float* Wout = (const float*)d_in[5];
    const float* bout = (const float*)d_in[6];
    float* out = (float*)d_out;

    actuatornet_kernel<<<dim3(NBLOCKS), dim3(TPB), 0, stream>>>(
        x, W1, b1, Wh, bh2, Wout, bout, out);
}

// Round 3
// 253.410 us; speedup vs baseline: 1.0170x; 1.0170x over previous
//
#include <hip/hip_runtime.h>
#include <hip/hip_bf16.h>

typedef __bf16 bf16x8 __attribute__((ext_vector_type(8)));
typedef float  f32x16 __attribute__((ext_vector_type(16)));
typedef float  f32x4  __attribute__((ext_vector_type(4)));

#define NLAYERS 19
#define BROWS   (1u << 20)
#define NTILES  (BROWS / 32)      // 32768 tiles of 32 rows
#define NBLOCKS 512               // 2 blocks/CU (LDS now < 80 KiB)
#define TPB     1024
#define NWAVES  (NBLOCKS * (TPB / 64))   // 8192 waves -> 4 tiles/wave

// ---- helpers ------------------------------------------------------------

// pack bf16(trunc(a)) into low16, bf16(trunc(b)) into high16 (one v_perm_b32)
__device__ __forceinline__ unsigned pack_hi(float a, float b) {
    return __builtin_amdgcn_perm(__float_as_uint(b), __float_as_uint(a), 0x07060302u);
}

// f32 value of the bf16-truncation of v (exact)
__device__ __forceinline__ float trunc_bf16_f32(float v) {
    return __uint_as_float(__float_as_uint(v) & 0xFFFF0000u);
}

__device__ __forceinline__ unsigned cvt_pk_bf16(float a, float b) {
    unsigned r;
    asm("v_cvt_pk_bf16_f32 %0, %1, %2" : "=v"(r) : "v"(a), "v"(b));
    return r;
}

__device__ __forceinline__ float fast_rcp(float a) {
    float r;
    asm("v_rcp_f32 %0, %1" : "=v"(r) : "v"(a));
    return r;
}

// v_permlane32_swap_b32: a' = [a.lo_lanes | b.lo_lanes], b' = [a.hi_lanes | b.hi_lanes]
__device__ __forceinline__ void pl32_swap(unsigned& a, unsigned& b) {
    asm volatile("v_permlane32_swap_b32 %0, %1" : "+v"(a), "+v"(b));
}

__device__ __forceinline__ unsigned short bf16_rne_bits(float f) {
    __hip_bfloat16 b = __float2bfloat16(f);
    return *reinterpret_cast<unsigned short*>(&b);
}

__device__ __forceinline__ f32x16 mfma(bf16x8 a, bf16x8 b, f32x16 c) {
    return __builtin_amdgcn_mfma_f32_32x32x16_bf16(a, b, c, 0, 0, 0);
}

union FragU { unsigned u[4]; bf16x8 v; };

// softsign 16 accumulator values -> sv[]
__device__ __forceinline__ void softsign16(const f32x16& c, float* sv) {
#pragma unroll
    for (int r = 0; r < 16; ++r) {
        float v = c[r];
        sv[r] = v * fast_rcp(1.0f + __builtin_fabsf(v));
    }
}

// Repack softsign outputs (C/D layout) into next-layer B fragments (hi/lo bf16).
// C/D: lane half h=lane>>5 holds feats (r&3)+8*(r>>2)+4h for r=0..15.
// B frag K-step s: lane half h needs feats 16s+8h+e, e=0..7.
__device__ __forceinline__ void repack(const float* sv, bf16x8* bhi, bf16x8* blo) {
#pragma unroll
    for (int s = 0; s < 2; ++s) {
        const float* p = sv + 8 * s;
        unsigned p00 = pack_hi(p[0], p[1]);
        unsigned p01 = pack_hi(p[2], p[3]);
        unsigned p10 = pack_hi(p[4], p[5]);
        unsigned p11 = pack_hi(p[6], p[7]);
        pl32_swap(p00, p10);
        pl32_swap(p01, p11);
        FragU H; H.u[0] = p00; H.u[1] = p01; H.u[2] = p10; H.u[3] = p11;
        bhi[s] = H.v;
        float l0 = p[0] - trunc_bf16_f32(p[0]);
        float l1 = p[1] - trunc_bf16_f32(p[1]);
        float l2 = p[2] - trunc_bf16_f32(p[2]);
        float l3 = p[3] - trunc_bf16_f32(p[3]);
        float l4 = p[4] - trunc_bf16_f32(p[4]);
        float l5 = p[5] - trunc_bf16_f32(p[5]);
        float l6 = p[6] - trunc_bf16_f32(p[6]);
        float l7 = p[7] - trunc_bf16_f32(p[7]);
        unsigned q00 = cvt_pk_bf16(l0, l1);
        unsigned q01 = cvt_pk_bf16(l2, l3);
        unsigned q10 = cvt_pk_bf16(l4, l5);
        unsigned q11 = cvt_pk_bf16(l6, l7);
        pl32_swap(q00, q10);
        pl32_swap(q01, q11);
        FragU L; L.u[0] = q00; L.u[1] = q01; L.u[2] = q10; L.u[3] = q11;
        blo[s] = L.v;
    }
}

// ---- kernel -------------------------------------------------------------

extern "C" __global__ void __launch_bounds__(TPB, 8)
actuatornet_kernel(const float* __restrict__ x,  const float* __restrict__ W1,
                   const float* __restrict__ b1, const float* __restrict__ Wh,
                   const float* __restrict__ bh, const float* __restrict__ Wout,
                   const float* __restrict__ bout, float* __restrict__ out)
{
    // LDS budget must stay <= 81920 B for 2 blocks/CU.
    __shared__ unsigned short s_wa_hi[NLAYERS * 2 * 64 * 8];   // 38912 B
    __shared__ unsigned short s_wa_lo[NLAYERS * 2 * 64 * 8];   // 38912 B
    __shared__ alignas(16) float s_bias[NLAYERS * 32];         // 2432 B, [lay][h][16] frag order
    __shared__ alignas(16) float s_b1a[32];                    // 128 B,  [h][16] frag order
    __shared__ alignas(16) float s_woa[32];                    // 128 B,  [h][16] frag order
    // total 80512 B

    const int tid = threadIdx.x;

    // ---- weight prep: split fp32 -> bf16 hi/lo in MFMA A-fragment order ----
    // A = W^T for layer `lay`, K-step s: lane l element e holds
    //   A[row = fo = l&31][k = fi-16s = 8*(l>>5)+e]  ==  W[fi][fo]
    for (int idx = tid; idx < NLAYERS * 2 * 64 * 8; idx += TPB) {
        int e = idx & 7, l = (idx >> 3) & 63, s = (idx >> 9) & 1, lay = idx >> 10;
        int fi = 16 * s + 8 * (l >> 5) + e;
        int fo = l & 31;
        float w = Wh[lay * 1024 + fi * 32 + fo];
        unsigned wb = __float_as_uint(w);
        s_wa_hi[idx] = (unsigned short)(wb >> 16);
        s_wa_lo[idx] = bf16_rne_bits(w - __uint_as_float(wb & 0xFFFF0000u));
    }
    // biases / Wout in C/D fragment order: entry [lay*32 + h*16 + r] = vec[(r&3)+8*(r>>2)+4h]
    for (int idx = tid; idx < NLAYERS * 32; idx += TPB) {
        int r = idx & 15, h2 = (idx >> 4) & 1, lay = idx >> 5;
        int f = (r & 3) + 8 * (r >> 2) + 4 * h2;
        s_bias[idx] = bh[lay * 32 + f];
    }
    if (tid < 32) {
        int r = tid & 15, h2 = tid >> 4;
        int f = (r & 3) + 8 * (r >> 2) + 4 * h2;
        s_b1a[tid] = b1[f];
        s_woa[tid] = Wout[f];
    }
    const float bout_v = bout[0];

    const int lane = tid & 63;
    const int col  = lane & 31;       // batch column within tile
    const int h    = lane >> 5;       // lane half
    const int wid  = blockIdx.x * (TPB / 64) + (tid >> 6);

    // ---- fc1 A-fragment: gather from global into registers (no LDS) ----
    // lane l element e: k = 8h+e (zero-pad k>=6), fo = col
    FragU A1H, A1L;
    {
        float w[8];
#pragma unroll
        for (int e = 0; e < 8; ++e) {
            int k = 8 * h + e;
            w[e] = (k < 6) ? W1[k * 32 + col] : 0.0f;
        }
#pragma unroll
        for (int j = 0; j < 4; ++j) {
            A1H.u[j] = pack_hi(w[2 * j], w[2 * j + 1]);
            A1L.u[j] = cvt_pk_bf16(w[2 * j]     - trunc_bf16_f32(w[2 * j]),
                                   w[2 * j + 1] - trunc_bf16_f32(w[2 * j + 1]));
        }
    }

    __syncthreads();

    const unsigned short* wa_hi_lane = s_wa_hi + lane * 8;
    const unsigned short* wa_lo_lane = s_wa_lo + lane * 8;
    const unsigned hm = (h == 0) ? 0xFFFFFFFFu : 0u;

    for (int tile = wid; tile < NTILES; tile += NWAVES) {
        const int base = tile * 32;

        // ---- fc1: load x row (6 floats), build B fragment (only h=0, e<6 nonzero)
        const float2* xr = (const float2*)(x + (size_t)(base + col) * 6);
        float2 xa = xr[0], xb = xr[1], xc = xr[2];
        FragU BH, BL;
        BH.u[0] = pack_hi(xa.x, xa.y) & hm;
        BH.u[1] = pack_hi(xb.x, xb.y) & hm;
        BH.u[2] = pack_hi(xc.x, xc.y) & hm;
        BH.u[3] = 0u;
        BL.u[0] = cvt_pk_bf16(xa.x - trunc_bf16_f32(xa.x), xa.y - trunc_bf16_f32(xa.y)) & hm;
        BL.u[1] = cvt_pk_bf16(xb.x - trunc_bf16_f32(xb.x), xb.y - trunc_bf16_f32(xb.y)) & hm;
        BL.u[2] = cvt_pk_bf16(xc.x - trunc_bf16_f32(xc.x), xc.y - trunc_bf16_f32(xc.y)) & hm;
        BL.u[3] = 0u;

        f32x16 c = *(const f32x16*)(s_b1a + h * 16);
        c = mfma(A1H.v, BH.v, c);
        c = mfma(A1H.v, BL.v, c);
        c = mfma(A1L.v, BH.v, c);

        float sv[16];
        softsign16(c, sv);
        bf16x8 hhi[2], hlo[2];
        repack(sv, hhi, hlo);

        // ---- 19 hidden layers
        for (int lay = 0; lay < NLAYERS; ++lay) {
            c = *(const f32x16*)(s_bias + lay * 32 + h * 16);
#pragma unroll
            for (int s = 0; s < 2; ++s) {
                const bf16x8 ah = *(const bf16x8*)(wa_hi_lane + (lay * 2 + s) * 512);
                const bf16x8 al = *(const bf16x8*)(wa_lo_lane + (lay * 2 + s) * 512);
                c = mfma(ah, hhi[s], c);
                c = mfma(ah, hlo[s], c);
                c = mfma(al, hhi[s], c);
            }
            softsign16(c, sv);
            if (lay != NLAYERS - 1) repack(sv, hhi, hlo);
        }

        // ---- fc6: dot(h, Wout) + bout
        const f32x16 wo = *(const f32x16*)(s_woa + h * 16);
        float dot = 0.0f;
#pragma unroll
        for (int r = 0; r < 16; ++r) dot += sv[r] * wo[r];
        float other = __shfl_xor(dot, 32, 64);
        dot += other;
        if (h == 0) out[base + col] = dot + bout_v;
    }
}

// ---- launch -------------------------------------------------------------

extern "C" void kernel_launch(void* const* d_in, const int* in_sizes, int n_in,
                              void* d_out, int out_size, void* d_ws, size_t ws_size,
                              hipStream_t stream) {
    const float* x    = (const float*)d_in[0];
    const float* W1   = (const float*)d_in[1];
    const float* b1   = (const float*)d_in[2];
    const float* Wh   = (const float*)d_in[3];
    const float* bh   = (const float*)d_in[4];
    const float* Wout = (const float*)d_in[5];
    const float* bout = (const float*)d_in[6];
    float* out = (float*)d_out;

    actuatornet_kernel<<<dim3(NBLOCKS), dim3(TPB), 0, stream>>>(
        x, W1, b1, Wh, bh, Wout, bout, out);
}

// Round 4
// 246.363 us; speedup vs baseline: 1.0461x; 1.0286x over previous
//
#include <hip/hip_runtime.h>
#include <hip/hip_bf16.h>

typedef __bf16 bf16x8 __attribute__((ext_vector_type(8)));
typedef float  f32x16 __attribute__((ext_vector_type(16)));

#define NLAYERS 19
#define BROWS   (1u << 20)
#define NPAIRS  (BROWS / 64)      // 16384 pairs of 32-row tiles (64 rows/wave/iter)
#define NBLOCKS 256
#define TPB     1024
#define NWAVES  (NBLOCKS * (TPB / 64))   // 4096 waves -> 4 pairs/wave

// ---- helpers ------------------------------------------------------------

// pack bf16(trunc(a)) into low16, bf16(trunc(b)) into high16 (one v_perm_b32)
__device__ __forceinline__ unsigned pack_hi(float a, float b) {
    return __builtin_amdgcn_perm(__float_as_uint(b), __float_as_uint(a), 0x07060302u);
}

// f32 value of the bf16-truncation of v (exact)
__device__ __forceinline__ float trunc_bf16_f32(float v) {
    return __uint_as_float(__float_as_uint(v) & 0xFFFF0000u);
}

__device__ __forceinline__ unsigned cvt_pk_bf16(float a, float b) {
    unsigned r;
    asm("v_cvt_pk_bf16_f32 %0, %1, %2" : "=v"(r) : "v"(a), "v"(b));
    return r;
}

__device__ __forceinline__ float fast_rcp(float a) {
    float r;
    asm("v_rcp_f32 %0, %1" : "=v"(r) : "v"(a));
    return r;
}

// v_permlane32_swap_b32: a' = [a.lo_lanes | b.lo_lanes], b' = [a.hi_lanes | b.hi_lanes]
__device__ __forceinline__ void pl32_swap(unsigned& a, unsigned& b) {
    asm volatile("v_permlane32_swap_b32 %0, %1" : "+v"(a), "+v"(b));
}

__device__ __forceinline__ unsigned short bf16_rne_bits(float f) {
    __hip_bfloat16 b = __float2bfloat16(f);
    return *reinterpret_cast<unsigned short*>(&b);
}

__device__ __forceinline__ f32x16 mfma(bf16x8 a, bf16x8 b, f32x16 c) {
    return __builtin_amdgcn_mfma_f32_32x32x16_bf16(a, b, c, 0, 0, 0);
}

union FragU { unsigned u[4]; bf16x8 v; };

// softsign 16 accumulator values -> sv[]
__device__ __forceinline__ void softsign16(const f32x16& c, float* sv) {
#pragma unroll
    for (int r = 0; r < 16; ++r) {
        float v = c[r];
        sv[r] = v * fast_rcp(1.0f + __builtin_fabsf(v));
    }
}

// Repack softsign outputs (C/D layout) into next-layer B fragments (hi/lo bf16).
// C/D: lane half h=lane>>5 holds feats (r&3)+8*(r>>2)+4h for r=0..15.
// B frag K-step s: lane half h needs feats 16s+8h+e, e=0..7.
__device__ __forceinline__ void repack(const float* sv, bf16x8* bhi, bf16x8* blo) {
#pragma unroll
    for (int s = 0; s < 2; ++s) {
        const float* p = sv + 8 * s;
        unsigned p00 = pack_hi(p[0], p[1]);
        unsigned p01 = pack_hi(p[2], p[3]);
        unsigned p10 = pack_hi(p[4], p[5]);
        unsigned p11 = pack_hi(p[6], p[7]);
        pl32_swap(p00, p10);
        pl32_swap(p01, p11);
        FragU H; H.u[0] = p00; H.u[1] = p01; H.u[2] = p10; H.u[3] = p11;
        bhi[s] = H.v;
        float l0 = p[0] - trunc_bf16_f32(p[0]);
        float l1 = p[1] - trunc_bf16_f32(p[1]);
        float l2 = p[2] - trunc_bf16_f32(p[2]);
        float l3 = p[3] - trunc_bf16_f32(p[3]);
        float l4 = p[4] - trunc_bf16_f32(p[4]);
        float l5 = p[5] - trunc_bf16_f32(p[5]);
        float l6 = p[6] - trunc_bf16_f32(p[6]);
        float l7 = p[7] - trunc_bf16_f32(p[7]);
        unsigned q00 = cvt_pk_bf16(l0, l1);
        unsigned q01 = cvt_pk_bf16(l2, l3);
        unsigned q10 = cvt_pk_bf16(l4, l5);
        unsigned q11 = cvt_pk_bf16(l6, l7);
        pl32_swap(q00, q10);
        pl32_swap(q01, q11);
        FragU L; L.u[0] = q00; L.u[1] = q01; L.u[2] = q10; L.u[3] = q11;
        blo[s] = L.v;
    }
}

// build fc1 B fragment (hi/lo) from a 6-float input row (only h=0, e<6 nonzero)
__device__ __forceinline__ void build_x_frag(const float* xp, unsigned hm,
                                             bf16x8& bh, bf16x8& bl) {
    const float2* xr = (const float2*)xp;
    float2 xa = xr[0], xb = xr[1], xc = xr[2];
    FragU BH, BL;
    BH.u[0] = pack_hi(xa.x, xa.y) & hm;
    BH.u[1] = pack_hi(xb.x, xb.y) & hm;
    BH.u[2] = pack_hi(xc.x, xc.y) & hm;
    BH.u[3] = 0u;
    BL.u[0] = cvt_pk_bf16(xa.x - trunc_bf16_f32(xa.x), xa.y - trunc_bf16_f32(xa.y)) & hm;
    BL.u[1] = cvt_pk_bf16(xb.x - trunc_bf16_f32(xb.x), xb.y - trunc_bf16_f32(xb.y)) & hm;
    BL.u[2] = cvt_pk_bf16(xc.x - trunc_bf16_f32(xc.x), xc.y - trunc_bf16_f32(xc.y)) & hm;
    BL.u[3] = 0u;
    bh = BH.v; bl = BL.v;
}

// ---- kernel -------------------------------------------------------------

extern "C" __global__ void __launch_bounds__(TPB, 4)
actuatornet_kernel(const float* __restrict__ x,  const float* __restrict__ W1,
                   const float* __restrict__ b1, const float* __restrict__ Wh,
                   const float* __restrict__ bh, const float* __restrict__ Wout,
                   const float* __restrict__ bout, float* __restrict__ out)
{
    __shared__ alignas(16) unsigned short s_wa_hi[NLAYERS * 2 * 64 * 8];   // 38912 B
    __shared__ alignas(16) unsigned short s_wa_lo[NLAYERS * 2 * 64 * 8];   // 38912 B
    __shared__ alignas(64) float s_bias[NLAYERS * 32];   // [lay][h][16] frag order
    __shared__ alignas(64) float s_b1a[32];              // [h][16] frag order
    __shared__ alignas(64) float s_woa[32];              // [h][16] frag order

    const int tid = threadIdx.x;

    // ---- weight prep: split fp32 -> bf16 hi/lo in MFMA A-fragment order ----
    // A = W^T for layer `lay`, K-step s: lane l element e holds
    //   A[row = fo = l&31][k = fi-16s = 8*(l>>5)+e]  ==  W[fi][fo]
    for (int idx = tid; idx < NLAYERS * 2 * 64 * 8; idx += TPB) {
        int e = idx & 7, l = (idx >> 3) & 63, s = (idx >> 9) & 1, lay = idx >> 10;
        int fi = 16 * s + 8 * (l >> 5) + e;
        int fo = l & 31;
        float w = Wh[lay * 1024 + fi * 32 + fo];
        unsigned wb = __float_as_uint(w);
        s_wa_hi[idx] = (unsigned short)(wb >> 16);
        s_wa_lo[idx] = bf16_rne_bits(w - __uint_as_float(wb & 0xFFFF0000u));
    }
    // biases / Wout in C/D fragment order: entry [lay*32 + h*16 + r] = vec[(r&3)+8*(r>>2)+4h]
    for (int idx = tid; idx < NLAYERS * 32; idx += TPB) {
        int r = idx & 15, h2 = (idx >> 4) & 1, lay = idx >> 5;
        int f = (r & 3) + 8 * (r >> 2) + 4 * h2;
        s_bias[idx] = bh[lay * 32 + f];
    }
    if (tid < 32) {
        int r = tid & 15, h2 = tid >> 4;
        int f = (r & 3) + 8 * (r >> 2) + 4 * h2;
        s_b1a[tid] = b1[f];
        s_woa[tid] = Wout[f];
    }
    const float bout_v = bout[0];

    const int lane = tid & 63;
    const int col  = lane & 31;       // batch column within tile
    const int h    = lane >> 5;       // lane half
    const int wid  = blockIdx.x * (TPB / 64) + (tid >> 6);

    // ---- fc1 A-fragment: gather from global into registers (no LDS) ----
    FragU A1H, A1L;
    {
        float w[8];
#pragma unroll
        for (int e = 0; e < 8; ++e) {
            int k = 8 * h + e;
            w[e] = (k < 6) ? W1[k * 32 + col] : 0.0f;
        }
#pragma unroll
        for (int j = 0; j < 4; ++j) {
            A1H.u[j] = pack_hi(w[2 * j], w[2 * j + 1]);
            A1L.u[j] = cvt_pk_bf16(w[2 * j]     - trunc_bf16_f32(w[2 * j]),
                                   w[2 * j + 1] - trunc_bf16_f32(w[2 * j + 1]));
        }
    }

    __syncthreads();

    const unsigned short* wa_hi_lane = s_wa_hi + lane * 8;
    const unsigned short* wa_lo_lane = s_wa_lo + lane * 8;
    const unsigned hm = (h == 0) ? 0xFFFFFFFFu : 0u;

    for (int pair = wid; pair < NPAIRS; pair += NWAVES) {
        const int baseA = pair * 64;
        const int baseB = baseA + 32;

        // ---- fc1 for both tiles
        bf16x8 BHa, BLa, BHb, BLb;
        build_x_frag(x + (size_t)(baseA + col) * 6, hm, BHa, BLa);
        build_x_frag(x + (size_t)(baseB + col) * 6, hm, BHb, BLb);

        const f32x16 cb1 = *(const f32x16*)(s_b1a + h * 16);
        f32x16 cA = mfma(A1H.v, BHa, cb1);
        cA = mfma(A1H.v, BLa, cA);
        cA = mfma(A1L.v, BHa, cA);
        f32x16 cB = mfma(A1H.v, BHb, cb1);
        cB = mfma(A1H.v, BLb, cB);
        cB = mfma(A1L.v, BHb, cB);

        float svA[16], svB[16];
        bf16x8 hA[2], lA[2], hB[2], lB[2];
        softsign16(cA, svA);
        repack(svA, hA, lA);
        softsign16(cB, svB);
        repack(svB, hB, lB);

        // ---- 19 hidden layers, 2 independent chains per wave
        for (int lay = 0; lay < NLAYERS; ++lay) {
            const bf16x8 ah0 = *(const bf16x8*)(wa_hi_lane + (lay * 2 + 0) * 512);
            const bf16x8 al0 = *(const bf16x8*)(wa_lo_lane + (lay * 2 + 0) * 512);
            const bf16x8 ah1 = *(const bf16x8*)(wa_hi_lane + (lay * 2 + 1) * 512);
            const bf16x8 al1 = *(const bf16x8*)(wa_lo_lane + (lay * 2 + 1) * 512);
            const f32x16 cb = *(const f32x16*)(s_bias + lay * 32 + h * 16);

            cA = mfma(ah0, hA[0], cb);      // bias folded in as C operand: free init
            cA = mfma(ah0, lA[0], cA);
            cA = mfma(al0, hA[0], cA);
            cA = mfma(ah1, hA[1], cA);
            cA = mfma(ah1, lA[1], cA);
            cA = mfma(al1, hA[1], cA);

            cB = mfma(ah0, hB[0], cb);
            cB = mfma(ah0, lB[0], cB);
            cB = mfma(al0, hB[0], cB);
            cB = mfma(ah1, hB[1], cB);
            cB = mfma(ah1, lB[1], cB);
            cB = mfma(al1, hB[1], cB);

            softsign16(cA, svA);
            softsign16(cB, svB);
            if (lay != NLAYERS - 1) {
                repack(svA, hA, lA);
                repack(svB, hB, lB);
            }
        }

        // ---- fc6: dot(h, Wout) + bout
        const f32x16 wo = *(const f32x16*)(s_woa + h * 16);
        float dA = 0.0f, dB = 0.0f;
#pragma unroll
        for (int r = 0; r < 16; ++r) { dA += svA[r] * wo[r]; dB += svB[r] * wo[r]; }
        dA += __shfl_xor(dA, 32, 64);
        dB += __shfl_xor(dB, 32, 64);
        if (h == 0) {
            out[baseA + col] = dA + bout_v;
            out[baseB + col] = dB + bout_v;
        }
    }
}

// ---- launch -------------------------------------------------------------

extern "C" void kernel_launch(void* const* d_in, const int* in_sizes, int n_in,
                              void* d_out, int out_size, void* d_ws, size_t ws_size,
                              hipStream_t stream) {
    const float* x    = (const float*)d_in[0];
    const float* W1   = (const float*)d_in[1];
    const float* b1   = (const float*)d_in[2];
    const float* Wh   = (const float*)d_in[3];
    const float* bh   = (const float*)d_in[4];
    const float* Wout = (const float*)d_in[5];
    const float* bout = (const float*)d_in[6];
    float* out = (float*)d_out;

    actuatornet_kernel<<<dim3(NBLOCKS), dim3(TPB), 0, stream>>>(
        x, W1, b1, Wh, bh, Wout, bout, out);
}